// Round 1
// baseline (226.196 us; speedup 1.0000x reference)
//
#include <hip/hip_runtime.h>

#define HW 3600
#define PADR 3712            // 29*128 padded rows
#define NF4 900
#define CAP 16384
#define KSEL 100
#define NT 58                // 64-col tiles
typedef unsigned long long U64;

using short8   = __attribute__((ext_vector_type(8))) short;
using float4v  = __attribute__((ext_vector_type(4))) float;
using float16v = __attribute__((ext_vector_type(16))) float;

__device__ __forceinline__ unsigned monof(float f) {
    unsigned b = __float_as_uint(f);
    return (b & 0x80000000u) ? ~b : (b | 0x80000000u);
}
__device__ __forceinline__ float unmonof(unsigned m) {
    return __uint_as_float((m & 0x80000000u) ? (m ^ 0x80000000u) : ~m);
}
__device__ __forceinline__ unsigned short f2bf(float f) {   // RNE
    unsigned b = __float_as_uint(f);
    return (unsigned short)((b + 0x7FFFu + ((b >> 16) & 1u)) >> 16);
}
__device__ __forceinline__ float bf2f(unsigned short h) {
    return __uint_as_float(((unsigned)h) << 16);
}
__device__ __forceinline__ void async16(const void* g, void* l) {
    __builtin_amdgcn_global_load_lds((const __attribute__((address_space(1))) void*)g,
                                     (__attribute__((address_space(3))) void*)l, 16, 0, 0);
}

// chunk-major element address (in shorts): buf[b][rblk][kb][row128][8]

// ---- Pass 0: convert x -> chunk-major split-bf16; zero den+cnt (no memset) -
__global__ __launch_bounds__(256) void conv_k(
    const float* __restrict__ x,
    unsigned short* __restrict__ hiT, unsigned short* __restrict__ loT,
    unsigned* __restrict__ zero_region)   // den(28800 f) ++ cnt(4) ++ tau(4)
{
    int b = blockIdx.z, l0 = blockIdx.x * 64, d0 = blockIdx.y * 64;
    __shared__ float t[64][65];
    int tid = threadIdx.x;
    if (blockIdx.y == 0 && blockIdx.z == 0) {
        int base = blockIdx.x * 512;
        for (int i = tid; i < 512; i += 256) {
            int g = base + i;
            if (g < 28808) zero_region[g] = 0u;
        }
    }
#pragma unroll
    for (int r = 0; r < 4; r++) {
        int idx = tid + 256 * r;              // 1024 float4 slots
        int d = idx >> 4, lq = idx & 15;
        int l = l0 + lq * 4;
        const float* src = x + ((size_t)b * 128 + d0 + d) * HW;
        float4 v;
        if (l + 3 < HW) v = *(const float4*)(src + l);
        else {
            v.x = (l     < HW) ? src[l]     : 0.f;
            v.y = (l + 1 < HW) ? src[l + 1] : 0.f;
            v.z = (l + 2 < HW) ? src[l + 2] : 0.f;
            v.w = (l + 3 < HW) ? src[l + 3] : 0.f;
        }
        t[lq * 4 + 0][d] = v.x; t[lq * 4 + 1][d] = v.y;
        t[lq * 4 + 2][d] = v.z; t[lq * 4 + 3][d] = v.w;
    }
    __syncthreads();
    const int rblk = l0 >> 7;
#pragma unroll
    for (int r = 0; r < 2; r++) {
        int idx = tid + 256 * r;              // 512 chunks of 8 bf16
        int l = idx & 63, dq = idx >> 6;      // row-inner -> coalesced stores
        unsigned hp[4], lp[4];
#pragma unroll
        for (int j = 0; j < 4; j++) {
            float f0 = t[l][dq * 8 + 2 * j], f1 = t[l][dq * 8 + 2 * j + 1];
            unsigned short h0 = f2bf(f0), h1 = f2bf(f1);
            unsigned short g0 = f2bf(f0 - bf2f(h0)), g1 = f2bf(f1 - bf2f(h1));
            hp[j] = (unsigned)h0 | ((unsigned)h1 << 16);
            lp[j] = (unsigned)g0 | ((unsigned)g1 << 16);
        }
        size_t o = ((size_t)(b * 29 + rblk) * 16 + (d0 >> 3) + dq) * 1024
                 + (size_t)((l0 + l) & 127) * 8;
        *(uint4*)(hiT + o) = make_uint4(hp[0], hp[1], hp[2], hp[3]);
        *(uint4*)(loT + o) = make_uint4(lp[0], lp[1], lp[2], lp[3]);
    }
}

// ---- Pass A: 512-thread 8-wave LDS-staged 32x32x16 GEMM; stats epilogue ----
// Double-buffered staging (T3 minimal 2-phase: issue next STAGE before compute,
// single __syncthreads per K-step -> its vmcnt(0) drain lands after compute has
// covered the load latency). Fused epilogue: ONE transpose pass produces both
// row-sum and row-max (max(v) = log(max(exp v)), err ~1e-7 << 3e-4 tau slack).
// Static LDS exactly 64KB: stats (2KB) + swizzled 32x32 transpose scratch
// (32KB) overlay the dead staging buffers during the epilogue.
__global__ __launch_bounds__(512) void gemm_mfma_k(
    const unsigned short* __restrict__ hiT, const unsigned short* __restrict__ loT,
    float* __restrict__ den_row, float* __restrict__ den_col,
    float* __restrict__ maxvt)
{
    const int batch = blockIdx.z, bx = blockIdx.x, by = blockIdx.y;
    __shared__ __align__(16) union SU {
        unsigned short st[2][4][4][128][8];   // 2 x 32768 B staging (double buffer)
        struct {                              // epilogue overlay (staging dead)
            float rs[128];                    // bytes 0..512      (over st[0])
            float cs[128];                    // 512..1024
            unsigned mx[256];                 // 1024..2048
            float pad[7680];                  // 2048..32768
            float T[8192];                    // 32768..65536      (over st[1]) 8 waves x 32x32
        } ep;
    } u;

    const int tid = threadIdx.x;
    const int lane = tid & 63, w = tid >> 6;          // 8 waves
    const int l31 = lane & 31, h = lane >> 5;
    const int p = w >> 1, halfr = w & 1;              // staging role
    const int rg = w >> 2, cg = w & 3;                // compute role

    const unsigned short* psrc = (p == 0) ? hiT : (p == 1) ? loT : (p == 2) ? hiT : loT;
    const int bsel = (p < 2) ? batch : batch + 4;
    const int rblk = (p < 2) ? by : bx;
    const size_t cbase = ((size_t)(bsel * 29 + rblk) * 16) * 1024;

    float16v acc[2];
    acc[0] = (float16v)(0.f);
    acc[1] = (float16v)(0.f);

    // prologue: stage k-chunk 0 into buffer 0
#pragma unroll
    for (int kb = 0; kb < 4; kb++) {
        const unsigned short* g = psrc + cbase + (size_t)kb * 1024 + (halfr << 9) + lane * 8;
        async16(g, &u.st[0][p][kb][halfr << 6][0]);
    }
    __syncthreads();

#pragma unroll
    for (int t = 0; t < 4; ++t) {
        const int cur = t & 1;
        if (t < 3) {                          // issue next-tile loads BEFORE compute
#pragma unroll
            for (int kb = 0; kb < 4; kb++) {
                const unsigned short* g = psrc + cbase + (size_t)((t + 1) * 4 + kb) * 1024
                                        + (halfr << 9) + lane * 8;
                async16(g, &u.st[cur ^ 1][p][kb][halfr << 6][0]);
            }
        }
#pragma unroll
        for (int j = 0; j < 2; j++) {
            int kb = j * 2 + h;
            short8 ah[2], al[2], bh, bl;
            ah[0] = *(const short8*)&u.st[cur][0][kb][rg * 64 + l31][0];
            ah[1] = *(const short8*)&u.st[cur][0][kb][rg * 64 + 32 + l31][0];
            al[0] = *(const short8*)&u.st[cur][1][kb][rg * 64 + l31][0];
            al[1] = *(const short8*)&u.st[cur][1][kb][rg * 64 + 32 + l31][0];
            bh    = *(const short8*)&u.st[cur][2][kb][cg * 32 + l31][0];
            bl    = *(const short8*)&u.st[cur][3][kb][cg * 32 + l31][0];
#pragma unroll
            for (int mt = 0; mt < 2; mt++) {
                acc[mt] = __builtin_amdgcn_mfma_f32_32x32x16_bf16(ah[mt], bh, acc[mt], 0, 0, 0);
                acc[mt] = __builtin_amdgcn_mfma_f32_32x32x16_bf16(ah[mt], bl, acc[mt], 0, 0, 0);
                acc[mt] = __builtin_amdgcn_mfma_f32_32x32x16_bf16(al[mt], bh, acc[mt], 0, 0, 0);
            }
        }
        __syncthreads();    // drains vmcnt (next-tile loads overlapped by compute above)
    }

    // ---- epilogue: init overlaid stats, then ONE fused transpose pass ------
    if (tid < 128) { u.ep.rs[tid] = 0.f; u.ep.cs[tid] = 0.f; }
    if (tid < 256) u.ep.mx[tid] = 0u;     // below every monof() value
    __syncthreads();

    // C/D: col = cg*32 + l31, row = rg*64 + mt*32 + (reg&3)+8*(reg>>2)+4*h
    const float scale = 0.078125f;   // 1/(128*0.1)
    float* T = u.ep.T + w * 1024;    // wave-private 32x32, XOR-swizzled
    const bool interior = (bx < 28) && (by < 28);
    const int col0 = bx * 128 + cg * 32 + l31;
    const bool cv = interior || (col0 < HW);
    float cs = 0.f;

#pragma unroll
    for (int mt = 0; mt < 2; mt++) {
#pragma unroll
        for (int reg = 0; reg < 16; reg++) {
            float v = acc[mt][reg] * scale;
            float e = cv ? __expf(v) : 0.f;
            int rloc = (reg & 3) + 8 * (reg >> 2) + 4 * h;
            bool rv = interior || (by * 128 + rg * 64 + mt * 32 + rloc < HW);
            if (rv) cs += e;
            T[rloc * 32 + (l31 ^ rloc)] = e;          // swizzled: addr = r*32 + (c^r)
        }
        __asm__ __volatile__("s_waitcnt lgkmcnt(0)" ::: "memory");
        {
            float ps = 0.f, pm = 0.f;
#pragma unroll
            for (int i = 0; i < 16; i++) {
                float tv_ = T[l31 * 32 + ((h * 16 + i) ^ l31)];
                ps += tv_;
                pm = fmaxf(pm, tv_);
            }
            ps += __shfl_xor(ps, 32);
            pm = fmaxf(pm, __shfl_xor(pm, 32));
            if (h == 0) {
                atomicAdd(&u.ep.rs[rg * 64 + mt * 32 + l31], ps);
                atomicMax(&u.ep.mx[(cg >> 1) * 128 + rg * 64 + mt * 32 + l31],
                          monof(__logf(pm)));        // max(v) = log(max(exp v))
            }
        }
        __asm__ __volatile__("s_waitcnt lgkmcnt(0)" ::: "memory");
    }
    // col sums: h pair covers complementary rows of the same column
    cs += __shfl_xor(cs, 32);
    if (h == 0) atomicAdd(&u.ep.cs[cg * 32 + l31], cs);
    __syncthreads();

    if (tid < 128) {
        int l = by * 128 + tid;
        if (l < HW) atomicAdd(&den_row[(size_t)batch * HW + l], u.ep.rs[tid]);
        int s = bx * 128 + tid;
        if (s < HW) atomicAdd(&den_col[(size_t)batch * HW + s], u.ep.cs[tid]);
    }
    if (tid < 256) {
        int tile = tid >> 7, row = tid & 127;
        int l = by * 128 + row;
        if (l < HW)
            maxvt[((size_t)batch * NT + bx * 2 + tile) * PADR + l] =
                unmonof(u.ep.mx[tile * 128 + row]);
    }
}

// ---- Pass B1: WIDE keylb: per-row champion-key lower bound -----------------
// keylb[j] = max_t (2*maxvt[t][j] - maxlnc[t]) - ln(den_row[j])
__global__ __launch_bounds__(256) void stat_k(
    const float* __restrict__ den_row, const float* __restrict__ den_col,
    const float* __restrict__ maxvt, float* __restrict__ keylb)
{
    const int b = blockIdx.z, tid = threadIdx.x;
    __shared__ float lncS[HW];
    __shared__ float mlsS[NT];
    for (int i = tid; i < HW; i += 256)
        lncS[i] = __logf(den_col[(size_t)b * HW + i]);
    __syncthreads();
    if (tid < NT) {
        float mx = -3.4e38f;
        int s0 = tid * 64, s1 = s0 + 64; if (s1 > HW) s1 = HW;
        for (int s = s0; s < s1; s++) mx = fmaxf(mx, lncS[s]);
        mlsS[tid] = (s0 < HW) ? mx : 1e30f;
    }
    __syncthreads();
    int j = blockIdx.x * 240 + tid;
    if (tid < 240 && j < HW) {
        const float* mvb = maxvt + (size_t)b * NT * PADR;
        float b0 = -3.4e38f, b1_ = -3.4e38f;
#pragma unroll 4
        for (int tt = 0; tt < 58; tt += 2) {
            b0  = fmaxf(b0,  2.0f * mvb[(size_t)tt * PADR + j]       - mlsS[tt]);
            b1_ = fmaxf(b1_, 2.0f * mvb[(size_t)(tt + 1) * PADR + j] - mlsS[tt + 1]);
        }
        keylb[(size_t)b * HW + j] = fmaxf(b0, b1_) - __logf(den_row[(size_t)b * HW + j]);
    }
}

// ---- Pass B2: exact 100th-largest keylb via 2-level hist + rank -> tau -----
__global__ __launch_bounds__(256) void tau_k(
    const float* __restrict__ keylb, float* __restrict__ tau)
{
    const int b = blockIdx.z, tid = threadIdx.x;
    __shared__ unsigned keyS[HW];
    __shared__ unsigned hist[4096];
    __shared__ unsigned hpc[256];
    __shared__ int b1S, c1S, b2S, lcnt;
    __shared__ unsigned bestS;
    __shared__ unsigned list[1024];

    for (int i = tid; i < 4096; i += 256) hist[i] = 0u;
    if (tid == 0) { lcnt = 0; bestS = 0u; }
    __syncthreads();
    for (int i = tid; i < HW; i += 256) {
        unsigned k = monof(keylb[(size_t)b * HW + i]);
        keyS[i] = k;
        atomicAdd(&hist[k >> 20], 1u);
    }
    __syncthreads();
    { unsigned s = 0; for (int j = 0; j < 16; j++) s += hist[tid * 16 + j]; hpc[tid] = s; }
    __syncthreads();
    if (tid == 0) {
        unsigned cum = 0; int cs_ = 255;
        for (; cs_ > 0; cs_--) { if (cum + hpc[cs_] >= (unsigned)KSEL) break; cum += hpc[cs_]; }
        int bb = cs_ * 16 + 15;
        for (; bb > cs_ * 16; bb--) { if (cum + hist[bb] >= (unsigned)KSEL) break; cum += hist[bb]; }
        b1S = bb; c1S = (int)cum;
    }
    __syncthreads();
    int b1 = b1S;
    for (int i = tid; i < 4096; i += 256) hist[i] = 0u;
    __syncthreads();
    for (int i = tid; i < HW; i += 256) {
        unsigned k = keyS[i];
        if ((int)(k >> 20) == b1) atomicAdd(&hist[(k >> 8) & 4095], 1u);
    }
    __syncthreads();
    { unsigned s = 0; for (int j = 0; j < 16; j++) s += hist[tid * 16 + j]; hpc[tid] = s; }
    __syncthreads();
    if (tid == 0) {
        unsigned cum = (unsigned)c1S; int cs_ = 255;
        for (; cs_ > 0; cs_--) { if (cum + hpc[cs_] >= (unsigned)KSEL) break; cum += hpc[cs_]; }
        int bb = cs_ * 16 + 15;
        for (; bb > cs_ * 16; bb--) { if (cum + hist[bb] >= (unsigned)KSEL) break; cum += hist[bb]; }
        b2S = bb;
    }
    __syncthreads();
    int b2 = b2S;
    for (int i = tid; i < HW; i += 256) {
        unsigned k = keyS[i]; int hb = (int)(k >> 20);
        if (hb > b1 || (hb == b1 && (int)((k >> 8) & 4095) >= b2)) {
            int p = atomicAdd(&lcnt, 1);
            if (p < 1024) list[p] = k;
        }
    }
    __syncthreads();
    int L = lcnt; if (L > 1024) L = 1024;
    for (int i = tid; i < L; i += 256) {
        unsigned e = list[i]; int c = 0;
        for (int j = 0; j < L; j++) c += (list[j] >= e) ? 1 : 0;
        if (c >= KSEL) atomicMax(&bestS, e);
    }
    __syncthreads();
    if (tid == 0) tau[b] = unmonof(bestS) - 3e-4f;   // slack: cross-kernel drift
}

// ---- Pass C: pairs + recompute + collect (R7 structure) --------------------
__global__ __launch_bounds__(256) void recollect_k(
    const unsigned short* __restrict__ hiT, const unsigned short* __restrict__ loT,
    const float* __restrict__ den_row, const float* __restrict__ den_col,
    const float* __restrict__ maxvt, const float* __restrict__ tau,
    uint2* __restrict__ cand, int* __restrict__ cnt)
{
    const int t = blockIdx.x, batch = blockIdx.y;
    const int tid = threadIdx.x;
    __shared__ float lnrS[HW];
    __shared__ float lncS[64];
    __shared__ int prS[2048];
    __shared__ int pcS;
    __shared__ float mnlS;

    if (tid < 64) {
        int c = t * 64 + tid;
        float lc = (c < HW) ? __logf(den_col[(size_t)batch * HW + c]) : 1e30f;
        lncS[tid] = lc;
        float mn = lc;
#pragma unroll
        for (int off = 1; off < 64; off <<= 1) mn = fminf(mn, __shfl_xor(mn, off));
        if (tid == 0) mnlS = mn;
    }
    for (int r = tid; r < HW; r += 256)
        lnrS[r] = __logf(den_row[(size_t)batch * HW + r]);
    if (tid == 0) pcS = 0;
    __syncthreads();

    const float tv = tau[batch];
    const float tvm = tv - 3e-4f;
    const float mnl = mnlS;
    const float* mv = maxvt + ((size_t)batch * NT + t) * PADR;
    for (int r = tid; r < HW; r += 256) {
        float bnd = 2.0f * mv[r] - lnrS[r] - mnl;
        if (bnd >= tvm) {
            int p = atomicAdd(&pcS, 1);
            if (p < 2048) prS[p] = r;
        }
    }
    __syncthreads();
    int pc = pcS; if (pc > 2048) pc = 2048;
    if (pc == 0) return;

    const int lane = tid & 63, w = tid >> 6;
    const int m = lane & 15, q = lane >> 4;
    const float scale = 0.078125f;
    const size_t abase = (size_t)batch * PADR * 128;
    const size_t bbase = (size_t)(batch + 4) * PADR * 128;

    for (int g = w; g * 16 < pc; g += 4) {
        int pi = g * 16 + m;
        int rowv = (pi < pc) ? prS[pi] : HW;       // pad rows are zeros
        float ldrv = (pi < pc) ? lnrS[rowv] : 0.f;
        size_t arow = abase + ((size_t)(rowv >> 7) * 16) * 1024 + (size_t)(rowv & 127) * 8;

        float4v acc[4];
#pragma unroll
        for (int i = 0; i < 4; i++) acc[i] = (float4v){0.f, 0.f, 0.f, 0.f};
#pragma unroll
        for (int k0 = 0; k0 < 128; k0 += 32) {
            int kb = (k0 >> 3) + q;
            short8 ah = *(const short8*)(hiT + arow + (size_t)kb * 1024);
            short8 al = *(const short8*)(loT + arow + (size_t)kb * 1024);
#pragma unroll
            for (int nt = 0; nt < 4; nt++) {
                int c = t * 64 + nt * 16 + m;
                size_t brow = bbase + ((size_t)(c >> 7) * 16 + kb) * 1024 + (size_t)(c & 127) * 8;
                short8 bh = *(const short8*)(hiT + brow);
                short8 bl = *(const short8*)(loT + brow);
                acc[nt] = __builtin_amdgcn_mfma_f32_16x16x32_bf16(ah, bh, acc[nt], 0, 0, 0);
                acc[nt] = __builtin_amdgcn_mfma_f32_16x16x32_bf16(ah, bl, acc[nt], 0, 0, 0);
                acc[nt] = __builtin_amdgcn_mfma_f32_16x16x32_bf16(al, bh, acc[nt], 0, 0, 0);
            }
        }
#pragma unroll
        for (int nt = 0; nt < 4; nt++) {
            int c = t * 64 + nt * 16 + m;
            if (c >= HW) continue;
            float ldc = lncS[nt * 16 + m];
#pragma unroll
            for (int r = 0; r < 4; r++) {
                int ri = q * 4 + r;
                if (g * 16 + ri >= pc) continue;
                int rowo = __shfl(rowv, ri);
                float ldro = __shfl(ldrv, ri);
                float v = acc[nt][r] * scale;
                float tt2 = 2.0f * v - ldro - ldc;
                if (tt2 >= tv) {
                    int p = atomicAdd(&cnt[batch], 1);
                    if (p < CAP)
                        cand[(size_t)batch * CAP + p] =
                            make_uint2(monof(tt2), (unsigned)(rowo * HW + c));
                }
            }
        }
    }
}

// ---- Pass D1: exact top-K selection ONCE per batch + embedding coefficients
// (hoisted out of the old final_k, which redid the O(M^2) rank in all 1024
// blocks; result depends only on batch). Writes cst[b8*128+d], sxy[d]/[128+d].
__global__ __launch_bounds__(1024) void select_k(
    const uint2* __restrict__ cand, const int* __restrict__ cnt,
    const float* __restrict__ W, const float* __restrict__ bias,
    float* __restrict__ cst, float* __restrict__ sxy)
{
    const int batch = blockIdx.x;
    const int tid = threadIdx.x;
    const uint2* cb = cand + (size_t)batch * CAP;
    __shared__ U64 lk[6144];
    __shared__ int topiS[KSEL];
    __shared__ float cqx[KSEL], cqy[KSEL], crx[KSEL], cry[KSEL];

    int M = cnt[batch]; if (M > CAP) M = CAP;
    const bool useL = (M <= 6144);
    if (useL)
        for (int i = tid; i < M; i += 1024) {
            uint2 e = cb[i];
            lk[i] = ((U64)e.x << 32) | (unsigned)(~e.y);
        }
    __syncthreads();
    for (int i = tid; i < M; i += 1024) {
        U64 e;
        if (useL) e = lk[i];
        else { uint2 tt = cb[i]; e = ((U64)tt.x << 32) | (unsigned)(~tt.y); }
        int r = 0;
        for (int j = 0; j < M; j++) {
            U64 o;
            if (useL) o = lk[j];
            else { uint2 tt = cb[j]; o = ((U64)tt.x << 32) | (unsigned)(~tt.y); }
            r += (o > e) ? 1 : 0;
        }
        if (r < KSEL) topiS[r] = (int)(~(unsigned)(e & 0xffffffffu));
    }
    __syncthreads();
    if (tid < KSEL) {
        int idx = topiS[tid];
        int qq = idx / HW, rr = idx - qq * HW;
        cqx[tid] = (float)(qq % 60) / 60.0f;
        cqy[tid] = (float)(qq / 60) / 60.0f;
        crx[tid] = (float)(rr % 60) / 60.0f;
        cry[tid] = (float)(rr / 60) / 60.0f;
    }
    __syncthreads();
    if (tid < 256) {
        const int d = tid & 127, hf = tid >> 7;
        const float* wrow = W + d * 200;
        float sx = 0.f, sy = 0.f, c = 0.f;
#pragma unroll 4
        for (int k = 0; k < KSEL; k++) {
            float wx = wrow[2 * k], wy = wrow[2 * k + 1];
            sx += wx; sy += wy;
            float cx = hf ? crx[k] : cqx[k];
            float cy = hf ? cry[k] : cqy[k];
            c += cx * wx + cy * wy;
        }
        cst[(hf ? (batch + 4) : batch) * 128 + d] = bias[d] - c;
        if (batch == 0 && hf == 0) { sxy[d] = sx; sxy[128 + d] = sy; }
    }
}

// ---- Pass D2: pure streaming elementwise output ----------------------------
__global__ __launch_bounds__(256) void final_k(
    const float* __restrict__ x, const float* __restrict__ cst,
    const float* __restrict__ sxy, float* __restrict__ out)
{
    const int bd = blockIdx.x;
    const int d = bd & 127;
    const int tid = threadIdx.x;
    const float cstv = cst[bd];
    const float sx = sxy[d], sy = sxy[128 + d];
    const float4* xin = (const float4*)(x + (size_t)bd * HW);
    float4* o4 = (float4*)(out + (size_t)bd * HW);
    for (int f = tid; f < NF4; f += 256) {
        float4 v = xin[f];
        int p0 = f * 4;
        float gy = (float)(p0 / 60) / 60.0f;
        float gxb = (float)(p0 % 60);
        float add = cstv + gy * sy;
        v.x += add + ((gxb      ) / 60.0f) * sx;
        v.y += add + ((gxb + 1.f) / 60.0f) * sx;
        v.z += add + ((gxb + 2.f) / 60.0f) * sx;
        v.w += add + ((gxb + 3.f) / 60.0f) * sx;
        o4[f] = v;
    }
}

extern "C" void kernel_launch(void* const* d_in, const int* in_sizes, int n_in,
                              void* d_out, int out_size, void* d_ws, size_t ws_size,
                              hipStream_t stream)
{
    const float* x    = (const float*)d_in[0];
    const float* W    = (const float*)d_in[1];
    const float* bias = (const float*)d_in[2];
    float* out = (float*)d_out;

    char* ws = (char*)d_ws;
    float*    den_row = (float*)(ws + 0);          // 57600
    float*    den_col = (float*)(ws + 57600);      // -> 115200
    int*      cnt     = (int*)  (ws + 115200);     // 16
    float*    tau     = (float*)(ws + 115216);     // 16 -> 115232 (conv zeroes 0..115232)
    float*    keylb   = (float*)(ws + 115264);     // 57600 -> 172864
    float*    cst     = (float*)(ws + 115264);     // reuses keylb (dead after tau_k): 4096
    float*    sxy     = (float*)(ws + 119360);     // 1024 -> 120384 (still inside keylb region)
    uint2*    cand    = (uint2*)(ws + 172864);     // 524288 -> 697152
    float*    maxvt   = (float*)(ws + 697152);     // 3444736 -> 4141888
    unsigned short* hiT = (unsigned short*)(ws + 4141888);   // 7602176 -> 11744064
    unsigned short* loT = (unsigned short*)(ws + 11744064);  // 7602176 -> 19346240

    conv_k     <<<dim3(58, 2, 8),  256, 0, stream>>>(x, hiT, loT, (unsigned*)ws);
    gemm_mfma_k<<<dim3(29, 29, 4), 512, 0, stream>>>(hiT, loT, den_row, den_col, maxvt);
    stat_k     <<<dim3(15, 1, 4),  256, 0, stream>>>(den_row, den_col, maxvt, keylb);
    tau_k      <<<dim3(1, 1, 4),   256, 0, stream>>>(keylb, tau);
    recollect_k<<<dim3(NT, 4),     256, 0, stream>>>(hiT, loT, den_row, den_col, maxvt, tau, cand, cnt);
    select_k   <<<dim3(4),         1024, 0, stream>>>(cand, cnt, W, bias, cst, sxy);
    final_k    <<<dim3(1024),      256, 0, stream>>>(x, cst, sxy, out);
}

// Round 2
// 224.558 us; speedup vs baseline: 1.0073x; 1.0073x over previous
//
#include <hip/hip_runtime.h>

#define HW 3600
#define PADR 3712            // 29*128 padded rows
#define NF4 900
#define CAP 16384
#define KSEL 100
#define NT 58                // 64-col tiles
typedef unsigned long long U64;

using short8   = __attribute__((ext_vector_type(8))) short;
using float4v  = __attribute__((ext_vector_type(4))) float;
using float16v = __attribute__((ext_vector_type(16))) float;

__device__ __forceinline__ unsigned monof(float f) {
    unsigned b = __float_as_uint(f);
    return (b & 0x80000000u) ? ~b : (b | 0x80000000u);
}
__device__ __forceinline__ float unmonof(unsigned m) {
    return __uint_as_float((m & 0x80000000u) ? (m ^ 0x80000000u) : ~m);
}
__device__ __forceinline__ unsigned short f2bf(float f) {   // RNE
    unsigned b = __float_as_uint(f);
    return (unsigned short)((b + 0x7FFFu + ((b >> 16) & 1u)) >> 16);
}
__device__ __forceinline__ float bf2f(unsigned short h) {
    return __uint_as_float(((unsigned)h) << 16);
}
__device__ __forceinline__ void async16(const void* g, void* l) {
    __builtin_amdgcn_global_load_lds((const __attribute__((address_space(1))) void*)g,
                                     (__attribute__((address_space(3))) void*)l, 16, 0, 0);
}

// chunk-major element address (in shorts): buf[b][rblk][kb][row128][8]

// ---- Pass 0: convert x -> chunk-major split-bf16; zero den+cnt (no memset) -
__global__ __launch_bounds__(256) void conv_k(
    const float* __restrict__ x,
    unsigned short* __restrict__ hiT, unsigned short* __restrict__ loT,
    unsigned* __restrict__ zero_region)   // den(28800 f) ++ cnt(4) ++ tau(4)
{
    int b = blockIdx.z, l0 = blockIdx.x * 64, d0 = blockIdx.y * 64;
    __shared__ float t[64][65];
    int tid = threadIdx.x;
    if (blockIdx.y == 0 && blockIdx.z == 0) {
        int base = blockIdx.x * 512;
        for (int i = tid; i < 512; i += 256) {
            int g = base + i;
            if (g < 28808) zero_region[g] = 0u;
        }
    }
#pragma unroll
    for (int r = 0; r < 4; r++) {
        int idx = tid + 256 * r;              // 1024 float4 slots
        int d = idx >> 4, lq = idx & 15;
        int l = l0 + lq * 4;
        const float* src = x + ((size_t)b * 128 + d0 + d) * HW;
        float4 v;
        if (l + 3 < HW) v = *(const float4*)(src + l);
        else {
            v.x = (l     < HW) ? src[l]     : 0.f;
            v.y = (l + 1 < HW) ? src[l + 1] : 0.f;
            v.z = (l + 2 < HW) ? src[l + 2] : 0.f;
            v.w = (l + 3 < HW) ? src[l + 3] : 0.f;
        }
        t[lq * 4 + 0][d] = v.x; t[lq * 4 + 1][d] = v.y;
        t[lq * 4 + 2][d] = v.z; t[lq * 4 + 3][d] = v.w;
    }
    __syncthreads();
    const int rblk = l0 >> 7;
#pragma unroll
    for (int r = 0; r < 2; r++) {
        int idx = tid + 256 * r;              // 512 chunks of 8 bf16
        int l = idx & 63, dq = idx >> 6;      // row-inner -> coalesced stores
        unsigned hp[4], lp[4];
#pragma unroll
        for (int j = 0; j < 4; j++) {
            float f0 = t[l][dq * 8 + 2 * j], f1 = t[l][dq * 8 + 2 * j + 1];
            unsigned short h0 = f2bf(f0), h1 = f2bf(f1);
            unsigned short g0 = f2bf(f0 - bf2f(h0)), g1 = f2bf(f1 - bf2f(h1));
            hp[j] = (unsigned)h0 | ((unsigned)h1 << 16);
            lp[j] = (unsigned)g0 | ((unsigned)g1 << 16);
        }
        size_t o = ((size_t)(b * 29 + rblk) * 16 + (d0 >> 3) + dq) * 1024
                 + (size_t)((l0 + l) & 127) * 8;
        *(uint4*)(hiT + o) = make_uint4(hp[0], hp[1], hp[2], hp[3]);
        *(uint4*)(loT + o) = make_uint4(lp[0], lp[1], lp[2], lp[3]);
    }
}

// ---- Pass A: 512-thread 8-wave LDS-staged 32x32x16 GEMM; stats epilogue ----
// Single-buffer staging (R1 post-mortem: dbuf cost occupancy 54->37% for -3%
// time; 4 blocks/CU TLP is the latency-hider). Fused epilogue: ONE transpose
// pass gives row-sum AND row-max (max(v)=log(max(exp v)), err ~1e-7 << 3e-4
// tau slack). Swizzled 32x32 scratch overlays staging (dead in epilogue).
__global__ __launch_bounds__(512) void gemm_mfma_k(
    const unsigned short* __restrict__ hiT, const unsigned short* __restrict__ loT,
    float* __restrict__ den_row, float* __restrict__ den_col,
    float* __restrict__ maxvt)
{
    const int batch = blockIdx.z, bx = blockIdx.x, by = blockIdx.y;
    __shared__ __align__(16) union SU {
        unsigned short st[4][4][128][8];   // 32768 B staging
        float T[8192];                     // epilogue: 8 waves x 32x32 swizzled
    } u;
    __shared__ float rsB[128];
    __shared__ float csB[128];
    __shared__ unsigned mxB[2][128];

    const int tid = threadIdx.x;
    const int lane = tid & 63, w = tid >> 6;          // 8 waves
    const int l31 = lane & 31, h = lane >> 5;
    const int p = w >> 1, halfr = w & 1;              // staging role
    const int rg = w >> 2, cg = w & 3;                // compute role

    if (tid < 128) { rsB[tid] = 0.f; csB[tid] = 0.f; }
    if (tid < 256) mxB[tid >> 7][tid & 127] = 0u;     // 0u < every monof(log) value

    const unsigned short* psrc = (p == 0) ? hiT : (p == 1) ? loT : (p == 2) ? hiT : loT;
    const int bsel = (p < 2) ? batch : batch + 4;
    const int rblk = (p < 2) ? by : bx;
    const size_t cbase = ((size_t)(bsel * 29 + rblk) * 16) * 1024;

    float16v acc[2];
    acc[0] = (float16v)(0.f);
    acc[1] = (float16v)(0.f);

    for (int k0 = 0; k0 < 128; k0 += 32) {
#pragma unroll
        for (int kb = 0; kb < 4; kb++) {
            const unsigned short* g = psrc + cbase + (size_t)((k0 >> 3) + kb) * 1024
                                    + (halfr << 9) + lane * 8;
            async16(g, &u.st[p][kb][halfr << 6][0]);
        }
        __syncthreads();
#pragma unroll
        for (int j = 0; j < 2; j++) {
            int kb = j * 2 + h;
            short8 ah[2], al[2], bh, bl;
            ah[0] = *(const short8*)&u.st[0][kb][rg * 64 + l31][0];
            ah[1] = *(const short8*)&u.st[0][kb][rg * 64 + 32 + l31][0];
            al[0] = *(const short8*)&u.st[1][kb][rg * 64 + l31][0];
            al[1] = *(const short8*)&u.st[1][kb][rg * 64 + 32 + l31][0];
            bh    = *(const short8*)&u.st[2][kb][cg * 32 + l31][0];
            bl    = *(const short8*)&u.st[3][kb][cg * 32 + l31][0];
#pragma unroll
            for (int mt = 0; mt < 2; mt++) {
                acc[mt] = __builtin_amdgcn_mfma_f32_32x32x16_bf16(ah[mt], bh, acc[mt], 0, 0, 0);
                acc[mt] = __builtin_amdgcn_mfma_f32_32x32x16_bf16(ah[mt], bl, acc[mt], 0, 0, 0);
                acc[mt] = __builtin_amdgcn_mfma_f32_32x32x16_bf16(al[mt], bh, acc[mt], 0, 0, 0);
            }
        }
        __syncthreads();
    }

    // ---- fused epilogue: one swizzled transpose pass -> rowsum + rowmax ----
    // C/D: col = cg*32 + l31, row = rg*64 + mt*32 + (reg&3)+8*(reg>>2)+4*h
    const float scale = 0.078125f;   // 1/(128*0.1)
    float* T = u.T + w * 1024;       // wave-private 32x32, XOR-swizzled
    const bool interior = (bx < 28) && (by < 28);
    const int col0 = bx * 128 + cg * 32 + l31;
    const bool cv = interior || (col0 < HW);
    float cs = 0.f;

#pragma unroll
    for (int mt = 0; mt < 2; mt++) {
#pragma unroll
        for (int reg = 0; reg < 16; reg++) {
            float v = acc[mt][reg] * scale;
            float e = cv ? __expf(v) : 0.f;
            int rloc = (reg & 3) + 8 * (reg >> 2) + 4 * h;
            bool rv = interior || (by * 128 + rg * 64 + mt * 32 + rloc < HW);
            if (rv) cs += e;
            T[rloc * 32 + (l31 ^ rloc)] = e;          // swizzled: addr = r*32 + (c^r)
        }
        __asm__ __volatile__("s_waitcnt lgkmcnt(0)" ::: "memory");
        {
            float ps = 0.f, pm = 0.f;
#pragma unroll
            for (int i = 0; i < 16; i++) {
                float tv_ = T[l31 * 32 + ((h * 16 + i) ^ l31)];
                ps += tv_;
                pm = fmaxf(pm, tv_);
            }
            ps += __shfl_xor(ps, 32);
            pm = fmaxf(pm, __shfl_xor(pm, 32));
            if (h == 0) {
                atomicAdd(&rsB[rg * 64 + mt * 32 + l31], ps);
                atomicMax(&mxB[cg >> 1][rg * 64 + mt * 32 + l31],
                          monof(__logf(pm)));        // max(v) = log(max(exp v))
            }
        }
        __asm__ __volatile__("s_waitcnt lgkmcnt(0)" ::: "memory");
    }
    // col sums: h pair covers complementary rows of the same column
    cs += __shfl_xor(cs, 32);
    if (h == 0) atomicAdd(&csB[cg * 32 + l31], cs);
    __syncthreads();

    if (tid < 128) {
        int l = by * 128 + tid;
        if (l < HW) atomicAdd(&den_row[(size_t)batch * HW + l], rsB[tid]);
        int s = bx * 128 + tid;
        if (s < HW) atomicAdd(&den_col[(size_t)batch * HW + s], csB[tid]);
    }
    if (tid < 256) {
        int tile = tid >> 7, row = tid & 127;
        int l = by * 128 + row;
        if (l < HW)
            maxvt[((size_t)batch * NT + bx * 2 + tile) * PADR + l] =
                unmonof(mxB[tile][row]);
    }
}

// ---- Pass B1: WIDE keylb: per-row champion-key lower bound -----------------
// keylb[j] = max_t (2*maxvt[t][j] - maxlnc[t]) - ln(den_row[j])
__global__ __launch_bounds__(256) void stat_k(
    const float* __restrict__ den_row, const float* __restrict__ den_col,
    const float* __restrict__ maxvt, float* __restrict__ keylb)
{
    const int b = blockIdx.z, tid = threadIdx.x;
    __shared__ float lncS[HW];
    __shared__ float mlsS[NT];
    for (int i = tid; i < HW; i += 256)
        lncS[i] = __logf(den_col[(size_t)b * HW + i]);
    __syncthreads();
    if (tid < NT) {
        float mx = -3.4e38f;
        int s0 = tid * 64, s1 = s0 + 64; if (s1 > HW) s1 = HW;
        for (int s = s0; s < s1; s++) mx = fmaxf(mx, lncS[s]);
        mlsS[tid] = (s0 < HW) ? mx : 1e30f;
    }
    __syncthreads();
    int j = blockIdx.x * 240 + tid;
    if (tid < 240 && j < HW) {
        const float* mvb = maxvt + (size_t)b * NT * PADR;
        float b0 = -3.4e38f, b1_ = -3.4e38f;
#pragma unroll 4
        for (int tt = 0; tt < 58; tt += 2) {
            b0  = fmaxf(b0,  2.0f * mvb[(size_t)tt * PADR + j]       - mlsS[tt]);
            b1_ = fmaxf(b1_, 2.0f * mvb[(size_t)(tt + 1) * PADR + j] - mlsS[tt + 1]);
        }
        keylb[(size_t)b * HW + j] = fmaxf(b0, b1_) - __logf(den_row[(size_t)b * HW + j]);
    }
}

// ---- Pass B2: exact 100th-largest keylb via 2-level hist + rank -> tau -----
__global__ __launch_bounds__(256) void tau_k(
    const float* __restrict__ keylb, float* __restrict__ tau)
{
    const int b = blockIdx.z, tid = threadIdx.x;
    __shared__ unsigned keyS[HW];
    __shared__ unsigned hist[4096];
    __shared__ unsigned hpc[256];
    __shared__ int b1S, c1S, b2S, lcnt;
    __shared__ unsigned bestS;
    __shared__ unsigned list[1024];

    for (int i = tid; i < 4096; i += 256) hist[i] = 0u;
    if (tid == 0) { lcnt = 0; bestS = 0u; }
    __syncthreads();
    for (int i = tid; i < HW; i += 256) {
        unsigned k = monof(keylb[(size_t)b * HW + i]);
        keyS[i] = k;
        atomicAdd(&hist[k >> 20], 1u);
    }
    __syncthreads();
    { unsigned s = 0; for (int j = 0; j < 16; j++) s += hist[tid * 16 + j]; hpc[tid] = s; }
    __syncthreads();
    if (tid == 0) {
        unsigned cum = 0; int cs_ = 255;
        for (; cs_ > 0; cs_--) { if (cum + hpc[cs_] >= (unsigned)KSEL) break; cum += hpc[cs_]; }
        int bb = cs_ * 16 + 15;
        for (; bb > cs_ * 16; bb--) { if (cum + hist[bb] >= (unsigned)KSEL) break; cum += hist[bb]; }
        b1S = bb; c1S = (int)cum;
    }
    __syncthreads();
    int b1 = b1S;
    for (int i = tid; i < 4096; i += 256) hist[i] = 0u;
    __syncthreads();
    for (int i = tid; i < HW; i += 256) {
        unsigned k = keyS[i];
        if ((int)(k >> 20) == b1) atomicAdd(&hist[(k >> 8) & 4095], 1u);
    }
    __syncthreads();
    { unsigned s = 0; for (int j = 0; j < 16; j++) s += hist[tid * 16 + j]; hpc[tid] = s; }
    __syncthreads();
    if (tid == 0) {
        unsigned cum = (unsigned)c1S; int cs_ = 255;
        for (; cs_ > 0; cs_--) { if (cum + hpc[cs_] >= (unsigned)KSEL) break; cum += hpc[cs_]; }
        int bb = cs_ * 16 + 15;
        for (; bb > cs_ * 16; bb--) { if (cum + hist[bb] >= (unsigned)KSEL) break; cum += hist[bb]; }
        b2S = bb;
    }
    __syncthreads();
    int b2 = b2S;
    for (int i = tid; i < HW; i += 256) {
        unsigned k = keyS[i]; int hb = (int)(k >> 20);
        if (hb > b1 || (hb == b1 && (int)((k >> 8) & 4095) >= b2)) {
            int p = atomicAdd(&lcnt, 1);
            if (p < 1024) list[p] = k;
        }
    }
    __syncthreads();
    int L = lcnt; if (L > 1024) L = 1024;
    for (int i = tid; i < L; i += 256) {
        unsigned e = list[i]; int c = 0;
        for (int j = 0; j < L; j++) c += (list[j] >= e) ? 1 : 0;
        if (c >= KSEL) atomicMax(&bestS, e);
    }
    __syncthreads();
    if (tid == 0) tau[b] = unmonof(bestS) - 3e-4f;   // slack: cross-kernel drift
}

// ---- Pass C: pairs + recompute + collect; B panel staged in LDS ------------
// Each (t,batch) block re-used its 64-col B panel (hi+lo, 64KB) from L2 for
// EVERY 16-row group -> latency chains. Now: stage it ONCE into 32KB LDS via
// 32 single-wave async16 slices (each (buf,kb) slice = 1024 contiguous bytes);
// inner loop reads B via conflict-free ds_read_b128. Identical MFMA order ->
// bit-identical tt2 vs previous version.
__global__ __launch_bounds__(256) void recollect_k(
    const unsigned short* __restrict__ hiT, const unsigned short* __restrict__ loT,
    const float* __restrict__ den_row, const float* __restrict__ den_col,
    const float* __restrict__ maxvt, const float* __restrict__ tau,
    uint2* __restrict__ cand, int* __restrict__ cnt)
{
    const int t = blockIdx.x, batch = blockIdx.y;
    const int tid = threadIdx.x;
    __shared__ float lnrS[HW];
    __shared__ float lncS[64];
    __shared__ int prS[2048];
    __shared__ int pcS;
    __shared__ float mnlS;
    __shared__ __align__(16) unsigned short bS[2][16][64][8];   // 32768 B

    const int lane = tid & 63, w = tid >> 6;
    const size_t bbase = (size_t)(batch + 4) * PADR * 128;

    // ---- stage B panel: cols t*64..t*64+63, full K, hi+lo ----
    // global row chunk for col c: bbase + ((c>>7)*16 + kb)*1024 + (c&127)*8
    // with c = t*64 + lane: (c>>7)=t>>1, (c&127)=(t&1)*64+lane  -> per (buf,kb)
    // slice is 64 lanes x 16B contiguous, linear into bS[buf][kb][lane][0..7].
    {
        const size_t sbase = bbase + (size_t)(t >> 1) * 16 * 1024
                           + (size_t)(t & 1) * 512 + (size_t)lane * 8;
#pragma unroll
        for (int s = w; s < 32; s += 4) {
            const int buf = s >> 4, kb = s & 15;
            const unsigned short* g = (buf ? loT : hiT) + sbase + (size_t)kb * 1024;
            async16(g, &bS[buf][kb][0][0]);
        }
    }

    if (tid < 64) {
        int c = t * 64 + tid;
        float lc = (c < HW) ? __logf(den_col[(size_t)batch * HW + c]) : 1e30f;
        lncS[tid] = lc;
        float mn = lc;
#pragma unroll
        for (int off = 1; off < 64; off <<= 1) mn = fminf(mn, __shfl_xor(mn, off));
        if (tid == 0) mnlS = mn;
    }
    for (int r = tid; r < HW; r += 256)
        lnrS[r] = __logf(den_row[(size_t)batch * HW + r]);
    if (tid == 0) pcS = 0;
    __syncthreads();

    const float tv = tau[batch];
    const float tvm = tv - 3e-4f;
    const float mnl = mnlS;
    const float* mv = maxvt + ((size_t)batch * NT + t) * PADR;
    for (int r = tid; r < HW; r += 256) {
        float bnd = 2.0f * mv[r] - lnrS[r] - mnl;
        if (bnd >= tvm) {
            int p = atomicAdd(&pcS, 1);
            if (p < 2048) prS[p] = r;
        }
    }
    __syncthreads();   // also drains the async16 B-stage (vmcnt(0) before barrier)
    int pc = pcS; if (pc > 2048) pc = 2048;
    if (pc == 0) return;

    const int m = lane & 15, q = lane >> 4;
    const float scale = 0.078125f;
    const size_t abase = (size_t)batch * PADR * 128;

    for (int g = w; g * 16 < pc; g += 4) {
        int pi = g * 16 + m;
        int rowv = (pi < pc) ? prS[pi] : HW;       // pad rows are zeros
        float ldrv = (pi < pc) ? lnrS[rowv] : 0.f;
        size_t arow = abase + ((size_t)(rowv >> 7) * 16) * 1024 + (size_t)(rowv & 127) * 8;

        float4v acc[4];
#pragma unroll
        for (int i = 0; i < 4; i++) acc[i] = (float4v){0.f, 0.f, 0.f, 0.f};
#pragma unroll
        for (int k0 = 0; k0 < 128; k0 += 32) {
            int kb = (k0 >> 3) + q;
            short8 ah = *(const short8*)(hiT + arow + (size_t)kb * 1024);
            short8 al = *(const short8*)(loT + arow + (size_t)kb * 1024);
#pragma unroll
            for (int nt = 0; nt < 4; nt++) {
                short8 bh = *(const short8*)&bS[0][kb][nt * 16 + m][0];
                short8 bl = *(const short8*)&bS[1][kb][nt * 16 + m][0];
                acc[nt] = __builtin_amdgcn_mfma_f32_16x16x32_bf16(ah, bh, acc[nt], 0, 0, 0);
                acc[nt] = __builtin_amdgcn_mfma_f32_16x16x32_bf16(ah, bl, acc[nt], 0, 0, 0);
                acc[nt] = __builtin_amdgcn_mfma_f32_16x16x32_bf16(al, bh, acc[nt], 0, 0, 0);
            }
        }
#pragma unroll
        for (int nt = 0; nt < 4; nt++) {
            int c = t * 64 + nt * 16 + m;
            if (c >= HW) continue;
            float ldc = lncS[nt * 16 + m];
#pragma unroll
            for (int r = 0; r < 4; r++) {
                int ri = q * 4 + r;
                if (g * 16 + ri >= pc) continue;
                int rowo = __shfl(rowv, ri);
                float ldro = __shfl(ldrv, ri);
                float v = acc[nt][r] * scale;
                float tt2 = 2.0f * v - ldro - ldc;
                if (tt2 >= tv) {
                    int p = atomicAdd(&cnt[batch], 1);
                    if (p < CAP)
                        cand[(size_t)batch * CAP + p] =
                            make_uint2(monof(tt2), (unsigned)(rowo * HW + c));
                }
            }
        }
    }
}

// ---- Pass D1: exact top-K selection ONCE per batch + embedding coefficients
__global__ __launch_bounds__(1024) void select_k(
    const uint2* __restrict__ cand, const int* __restrict__ cnt,
    const float* __restrict__ W, const float* __restrict__ bias,
    float* __restrict__ cst, float* __restrict__ sxy)
{
    const int batch = blockIdx.x;
    const int tid = threadIdx.x;
    const uint2* cb = cand + (size_t)batch * CAP;
    __shared__ U64 lk[6144];
    __shared__ int topiS[KSEL];
    __shared__ float cqx[KSEL], cqy[KSEL], crx[KSEL], cry[KSEL];

    int M = cnt[batch]; if (M > CAP) M = CAP;
    const bool useL = (M <= 6144);
    if (useL)
        for (int i = tid; i < M; i += 1024) {
            uint2 e = cb[i];
            lk[i] = ((U64)e.x << 32) | (unsigned)(~e.y);
        }
    __syncthreads();
    for (int i = tid; i < M; i += 1024) {
        U64 e;
        if (useL) e = lk[i];
        else { uint2 tt = cb[i]; e = ((U64)tt.x << 32) | (unsigned)(~tt.y); }
        int r = 0;
        for (int j = 0; j < M; j++) {
            U64 o;
            if (useL) o = lk[j];
            else { uint2 tt = cb[j]; o = ((U64)tt.x << 32) | (unsigned)(~tt.y); }
            r += (o > e) ? 1 : 0;
        }
        if (r < KSEL) topiS[r] = (int)(~(unsigned)(e & 0xffffffffu));
    }
    __syncthreads();
    if (tid < KSEL) {
        int idx = topiS[tid];
        int qq = idx / HW, rr = idx - qq * HW;
        cqx[tid] = (float)(qq % 60) / 60.0f;
        cqy[tid] = (float)(qq / 60) / 60.0f;
        crx[tid] = (float)(rr % 60) / 60.0f;
        cry[tid] = (float)(rr / 60) / 60.0f;
    }
    __syncthreads();
    if (tid < 256) {
        const int d = tid & 127, hf = tid >> 7;
        const float* wrow = W + d * 200;
        float sx = 0.f, sy = 0.f, c = 0.f;
#pragma unroll 4
        for (int k = 0; k < KSEL; k++) {
            float wx = wrow[2 * k], wy = wrow[2 * k + 1];
            sx += wx; sy += wy;
            float cx = hf ? crx[k] : cqx[k];
            float cy = hf ? cry[k] : cqy[k];
            c += cx * wx + cy * wy;
        }
        cst[(hf ? (batch + 4) : batch) * 128 + d] = bias[d] - c;
        if (batch == 0 && hf == 0) { sxy[d] = sx; sxy[128 + d] = sy; }
    }
}

// ---- Pass D2: pure streaming elementwise output ----------------------------
__global__ __launch_bounds__(256) void final_k(
    const float* __restrict__ x, const float* __restrict__ cst,
    const float* __restrict__ sxy, float* __restrict__ out)
{
    const int bd = blockIdx.x;
    const int d = bd & 127;
    const int tid = threadIdx.x;
    const float cstv = cst[bd];
    const float sx = sxy[d], sy = sxy[128 + d];
    const float4* xin = (const float4*)(x + (size_t)bd * HW);
    float4* o4 = (float4*)(out + (size_t)bd * HW);
    for (int f = tid; f < NF4; f += 256) {
        float4 v = xin[f];
        int p0 = f * 4;
        float gy = (float)(p0 / 60) / 60.0f;
        float gxb = (float)(p0 % 60);
        float add = cstv + gy * sy;
        v.x += add + ((gxb      ) / 60.0f) * sx;
        v.y += add + ((gxb + 1.f) / 60.0f) * sx;
        v.z += add + ((gxb + 2.f) / 60.0f) * sx;
        v.w += add + ((gxb + 3.f) / 60.0f) * sx;
        o4[f] = v;
    }
}

extern "C" void kernel_launch(void* const* d_in, const int* in_sizes, int n_in,
                              void* d_out, int out_size, void* d_ws, size_t ws_size,
                              hipStream_t stream)
{
    const float* x    = (const float*)d_in[0];
    const float* W    = (const float*)d_in[1];
    const float* bias = (const float*)d_in[2];
    float* out = (float*)d_out;

    char* ws = (char*)d_ws;
    float*    den_row = (float*)(ws + 0);          // 57600
    float*    den_col = (float*)(ws + 57600);      // -> 115200
    int*      cnt     = (int*)  (ws + 115200);     // 16
    float*    tau     = (float*)(ws + 115216);     // 16 -> 115232 (conv zeroes 0..115232)
    float*    keylb   = (float*)(ws + 115264);     // 57600 -> 172864
    float*    cst     = (float*)(ws + 115264);     // reuses keylb (dead after tau_k): 4096
    float*    sxy     = (float*)(ws + 119360);     // 1024 -> 120384 (inside keylb region)
    uint2*    cand    = (uint2*)(ws + 172864);     // 524288 -> 697152
    float*    maxvt   = (float*)(ws + 697152);     // 3444736 -> 4141888
    unsigned short* hiT = (unsigned short*)(ws + 4141888);   // 7602176 -> 11744064
    unsigned short* loT = (unsigned short*)(ws + 11744064);  // 7602176 -> 19346240

    conv_k     <<<dim3(58, 2, 8),  256, 0, stream>>>(x, hiT, loT, (unsigned*)ws);
    gemm_mfma_k<<<dim3(29, 29, 4), 512, 0, stream>>>(hiT, loT, den_row, den_col, maxvt);
    stat_k     <<<dim3(15, 1, 4),  256, 0, stream>>>(den_row, den_col, maxvt, keylb);
    tau_k      <<<dim3(1, 1, 4),   256, 0, stream>>>(keylb, tau);
    recollect_k<<<dim3(NT, 4),     256, 0, stream>>>(hiT, loT, den_row, den_col, maxvt, tau, cand, cnt);
    select_k   <<<dim3(4),         1024, 0, stream>>>(cand, cnt, W, bias, cst, sxy);
    final_k    <<<dim3(1024),      256, 0, stream>>>(x, cst, sxy, out);
}